// Round 6
// baseline (888.294 us; speedup 1.0000x reference)
//
#include <hip/hip_runtime.h>
#include <hip/hip_bf16.h>
#include <stdint.h>

#define DEVI __device__ __forceinline__

typedef __attribute__((ext_vector_type(8))) __bf16 bf16x8;
typedef __attribute__((ext_vector_type(4))) float f32x4;

DEVI unsigned short f2b(float f) {
  union { float f; unsigned int u; } x; x.f = f;
  unsigned int u = x.u;
  return (unsigned short)((u + 0x7fffu + ((u >> 16) & 1u)) >> 16);
}

// ---------------- fp32 -> bf16 convert (vectorized) ----------------
__global__ void cvt_kernel(const float* __restrict__ in,
                           unsigned short* __restrict__ out, long n4) {
  long i = (long)blockIdx.x * blockDim.x + threadIdx.x;
  long stride = (long)gridDim.x * blockDim.x;
  for (; i < n4; i += stride) {
    float4 v = reinterpret_cast<const float4*>(in)[i];
    ushort4 o;
    o.x = f2b(v.x); o.y = f2b(v.y); o.z = f2b(v.z); o.w = f2b(v.w);
    reinterpret_cast<ushort4*>(out)[i] = o;
  }
}

// ------------- [b][P][D] fp32 -> [b][D][P] bf16 transpose -------------
__global__ void transpose_cvt_kernel(const float* __restrict__ in,
                                     unsigned short* __restrict__ out,
                                     int P, int D) {
  __shared__ unsigned short tile[32][33];
  int b = blockIdx.z;
  int d0 = blockIdx.x * 32, p0 = blockIdx.y * 32;
  const float* src = in + (long)b * P * D;
  unsigned short* dst = out + (long)b * D * P;
  int tx = threadIdx.x & 31, ty = threadIdx.x >> 5; // 32 x 8
  for (int i = 0; i < 32; i += 8)
    tile[ty + i][tx] = f2b(src[(long)(p0 + ty + i) * D + d0 + tx]);
  __syncthreads();
  for (int i = 0; i < 32; i += 8)
    dst[(long)(d0 + ty + i) * P + p0 + tx] = tile[tx][ty + i];
}

// ---- u[y] = sum_d W[d][y] * v[d]   (atomic-split column GEMV) ----
__global__ void gemv_col_kernel(const float* __restrict__ W,
                                const float* __restrict__ v,
                                float* __restrict__ u, int D) {
  int y = blockIdx.x * 256 + threadIdx.x;
  int d0 = blockIdx.y * 128;
  float s = 0.f;
  for (int d = d0; d < d0 + 128; ++d) s += W[(long)d * D + y] * v[d];
  atomicAdd(&u[y], s);
}

// ---- c[row] = sum_y feat[row][y] * u[y]  (one wave per row) ----
__global__ void rowdot_kernel(const float* __restrict__ feat,
                              const float* __restrict__ u,
                              float* __restrict__ c, int D) {
  long row = (long)blockIdx.x * 4 + (threadIdx.x >> 6);
  int lane = threadIdx.x & 63;
  const float4* fr = (const float4*)(feat + row * D);
  const float4* uv = (const float4*)u;
  float s = 0.f;
  for (int j = lane; j < D / 4; j += 64) {
    float4 f = fr[j], g = uv[j];
    s += f.x * g.x + f.y * g.y + f.z * g.z + f.w * g.w;
  }
#pragma unroll
  for (int o = 32; o > 0; o >>= 1) s += __shfl_xor(s, o, 64);
  if (lane == 0) c[row] = s;
}

// ---------------- async global->LDS 16B ----------------
DEVI void gll16(const void* g, void* l) {
  __builtin_amdgcn_global_load_lds(
      (const __attribute__((address_space(1))) unsigned int*)g,
      (__attribute__((address_space(3))) unsigned int*)l, 16, 0, 0);
}

// ======================= 8-phase 256x256 NT GEMM =======================
// C[M][N] = A[M][K] * B[N][K]^T, bf16 in/out, fp32 acc.
// M,N multiples of 256; K multiple of 128. 512 threads = 8 waves (2M x 4N).
// LDS 128 KiB: per matrix a ring of 4 half-slots (128 rows x 64 K = 16 KB),
// ring = {dbuf 2} x {half 2}. Linear row-major [128][64] layout (m198 config).
// Per iter: 2 K-tiles (BK=64), 8 phases, gray-code quadrants; staging runs
// 7 half-tiles ahead; counted vmcnt(6) at phases 4/8 only (vmcnt(0) only in
// the last iteration). All LDS reads are inline-asm ds_read_b128 (opaque to
// the waitcnt pass -> no compiler-inserted vmcnt(0) drains) with manual
// lgkmcnt(0) + sched_barrier(0) per rule 18.

#define DSR(dst, base, IMM) \
  asm volatile("ds_read_b128 %0, %1 offset:" IMM : "=v"(dst) : "v"(base))

#define READ_AF(AF, BASE) do { \
  DSR(AF[0][0], BASE, "0");    DSR(AF[0][1], BASE, "64");   \
  DSR(AF[1][0], BASE, "2048"); DSR(AF[1][1], BASE, "2112"); \
  DSR(AF[2][0], BASE, "4096"); DSR(AF[2][1], BASE, "4160"); \
  DSR(AF[3][0], BASE, "6144"); DSR(AF[3][1], BASE, "6208"); \
} while (0)

#define READ_BF(BF, BASE) do { \
  DSR(BF[0][0], BASE, "0");    DSR(BF[0][1], BASE, "64");   \
  DSR(BF[1][0], BASE, "2048"); DSR(BF[1][1], BASE, "2112"); \
} while (0)

#define MFMA16(AF, BF, QM, QN) do { \
  _Pragma("unroll") \
  for (int j_ = 0; j_ < 4; ++j_) { \
    _Pragma("unroll") \
    for (int n_ = 0; n_ < 2; ++n_) { \
      acc[QM][QN][j_][n_] = __builtin_amdgcn_mfma_f32_16x16x32_bf16( \
          AF[j_][0], BF[n_][0], acc[QM][QN][j_][n_], 0, 0, 0); \
      acc[QM][QN][j_][n_] = __builtin_amdgcn_mfma_f32_16x16x32_bf16( \
          AF[j_][1], BF[n_][1], acc[QM][QN][j_][n_], 0, 0, 0); \
    } \
  } \
} while (0)

#define VMC6() asm volatile("s_waitcnt vmcnt(6)")
#define VMC0() asm volatile("s_waitcnt vmcnt(0)")
#define PRE()  do { __builtin_amdgcn_s_barrier(); \
                    asm volatile("s_waitcnt lgkmcnt(0)"); \
                    __builtin_amdgcn_sched_barrier(0); \
                    __builtin_amdgcn_s_setprio(1); } while (0)
#define POST() do { __builtin_amdgcn_s_setprio(0); \
                    __builtin_amdgcn_s_barrier(); } while (0)

__global__ __launch_bounds__(512, 2) void gemm8_nt_kernel(
    const unsigned short* __restrict__ A,
    const unsigned short* __restrict__ B,
    unsigned short* __restrict__ C,
    int M, int N, int K) {
  __shared__ unsigned short lds[65536];  // 128 KiB

  const int tid = threadIdx.x;
  const int lane = tid & 63;
  const int w = tid >> 6;
  const int wm = w >> 2, wn = w & 3;
  const int m0 = blockIdx.y * 256;
  const int n0 = blockIdx.x * 256;

  const int NIT = K >> 7;    // iters (128 K each)
  const int HMAX = K >> 4;   // total half-tiles (4 per 64-K tile)

  // staging source bases: row = base + h*128 + i*64, col = T*64 + (l&7)*8
  const int srow = w * 8 + (lane >> 3);
  const int scol = (lane & 7) * 8;
  const unsigned short* Ag = A + (long)(m0 + srow) * K + scol;
  const unsigned short* Bg = B + (long)(n0 + srow) * K + scol;

  const unsigned ldsbase =
      (unsigned)(size_t)(__attribute__((address_space(3))) unsigned short*)lds;

  auto stage = [&](int H) {
    if (H >= HMAX) return;
    const int T = H >> 2, part = H & 3;
    const int isB = part & 1, h = part >> 1;
    const unsigned short* src =
        (isB ? Bg : Ag) + (long)(h * 128) * K + (long)T * 64;
    char* d0 = (char*)lds + isB * 65536 + ((T & 1) * 2 + h) * 16384 + w * 1024;
    gll16(src, d0);
    gll16(src + (long)64 * K, d0 + 8192);
  };

  // per-thread ds_read bases (loop-invariant): [dbuf][half]
  const unsigned aoff = (unsigned)((wm * 64 + (lane & 15)) * 128 + (lane >> 4) * 16);
  const unsigned boff = (unsigned)((wn * 32 + (lane & 15)) * 128 + (lane >> 4) * 16);
  const unsigned bA00 = ldsbase + 0 * 16384 + aoff;
  const unsigned bA01 = ldsbase + 1 * 16384 + aoff;
  const unsigned bA10 = ldsbase + 2 * 16384 + aoff;
  const unsigned bA11 = ldsbase + 3 * 16384 + aoff;
  const unsigned bB00 = ldsbase + 65536 + 0 * 16384 + boff;
  const unsigned bB01 = ldsbase + 65536 + 1 * 16384 + boff;
  const unsigned bB10 = ldsbase + 65536 + 2 * 16384 + boff;
  const unsigned bB11 = ldsbase + 65536 + 3 * 16384 + boff;

  f32x4 acc[2][2][4][2];
#pragma unroll
  for (int a = 0; a < 2; ++a)
#pragma unroll
    for (int bq = 0; bq < 2; ++bq)
#pragma unroll
      for (int j = 0; j < 4; ++j)
#pragma unroll
        for (int n = 0; n < 2; ++n) acc[a][bq][j][n] = (f32x4){0.f, 0.f, 0.f, 0.f};

  bf16x8 af0[4][2], af1[4][2], bfr[2][2];

  // prologue: 7 half-tiles (tile0 complete + tile1 A0,B0,A1)
  stage(0); stage(1); stage(2); stage(3); stage(4); stage(5); stage(6);
  VMC6();  // tile 0 fully resident
  __builtin_amdgcn_s_barrier();

  for (int i = 0; i < NIT; ++i) {
    const int Hb = 7 + 8 * i;
    const bool last = (i == NIT - 1);
    // ---- tile 2i (dbuf 0) ----
    // p0: (qm0,qn0)
    READ_AF(af0, bA00); READ_BF(bfr, bB00);
    stage(Hb + 0);
    PRE(); MFMA16(af0, bfr, 0, 0); POST();
    // p1: (qm1,qn0)
    READ_AF(af1, bA01);
    stage(Hb + 1);
    PRE(); MFMA16(af1, bfr, 1, 0); POST();
    // p2: (qm1,qn1)
    READ_BF(bfr, bB01);
    stage(Hb + 2);
    PRE(); MFMA16(af1, bfr, 1, 1); POST();
    // p3: (qm0,qn1)
    stage(Hb + 3);
    if (last) { VMC0(); } else { VMC6(); }
    PRE(); MFMA16(af0, bfr, 0, 1); POST();
    // ---- tile 2i+1 (dbuf 1) ----
    // p4
    READ_AF(af0, bA10); READ_BF(bfr, bB10);
    stage(Hb + 4);
    PRE(); MFMA16(af0, bfr, 0, 0); POST();
    // p5
    READ_AF(af1, bA11);
    stage(Hb + 5);
    PRE(); MFMA16(af1, bfr, 1, 0); POST();
    // p6
    READ_BF(bfr, bB11);
    stage(Hb + 6);
    PRE(); MFMA16(af1, bfr, 1, 1); POST();
    // p7
    stage(Hb + 7);
    VMC6();
    PRE(); MFMA16(af0, bfr, 0, 1); POST();
  }

  // epilogue: row = m0 + qm*128 + wm*64 + j*16 + (lane>>4)*4 + r
  //           col = n0 + qn*128 + wn*32 + n*16 + (lane&15)
#pragma unroll
  for (int qm = 0; qm < 2; ++qm)
#pragma unroll
    for (int qn = 0; qn < 2; ++qn)
#pragma unroll
      for (int j = 0; j < 4; ++j)
#pragma unroll
        for (int n = 0; n < 2; ++n) {
          const int gr0 = m0 + qm * 128 + wm * 64 + j * 16 + (lane >> 4) * 4;
          const int gc = n0 + qn * 128 + wn * 32 + n * 16 + (lane & 15);
#pragma unroll
          for (int r = 0; r < 4; ++r)
            C[(long)(gr0 + r) * N + gc] = f2b(acc[qm][qn][j][n][r]);
        }
}

// ---------------- generic NT GEMM (2-barrier dbuf): C = (A * B^T + colbias) * scale ----------------
template<int OUT_BF16, int HAS_BIAS, int CLAMP_N, int BATCH_X>
__global__ __launch_bounds__(256, 3) void gemm_nt_kernel(
    const unsigned short* __restrict__ A,
    const unsigned short* __restrict__ B,
    void* __restrict__ Cv,
    const float* __restrict__ bias,
    float scale, int M, int N, int K,
    long sA, long sB, long sC, long sBias) {
  __shared__ unsigned short As[2][128 * 32];
  __shared__ unsigned short Bs[2][128 * 32];

  const int tid = threadIdx.x;
  const int lane = tid & 63;
  const int wid = tid >> 6;

  int bx = blockIdx.x;
  int b;
  if (BATCH_X) { b = bx & 7; bx >>= 3; } else { b = blockIdx.z; }
  const int n0 = bx * 128;
  const int m0 = blockIdx.y * 128;

  const unsigned short* Ab = A + (long)b * sA;
  const unsigned short* Bb = B + (long)b * sB;
  const float* biasb = HAS_BIAS ? bias + (long)b * sBias : nullptr;

  const int srow = lane >> 2;
  const int scol = (lane & 3) * 8;

  auto stage = [&](int k0, int buf) {
#pragma unroll
    for (int i = 0; i < 2; ++i) {
      const int j = wid * 2 + i;
      const int ra = m0 + j * 16 + srow;
      gll16(Ab + (long)ra * K + k0 + scol, (void*)(As[buf] + j * 512));
      int rb = n0 + j * 16 + srow;
      if (CLAMP_N) rb = min(rb, N - 1);
      gll16(Bb + (long)rb * K + k0 + scol, (void*)(Bs[buf] + j * 512));
    }
  };

  f32x4 acc[4][4];
#pragma unroll
  for (int m = 0; m < 4; ++m)
#pragma unroll
    for (int n = 0; n < 4; ++n) acc[m][n] = (f32x4){0.f, 0.f, 0.f, 0.f};

  const int wm = wid >> 1;
  const int wn = wid & 1;
  const int lrow = lane & 15;
  const int lkb = (lane >> 4) * 8;

  stage(0, 0);
  __syncthreads();

  int cur = 0;
  for (int k0 = 0; k0 < K; k0 += 32) {
    if (k0 + 32 < K) stage(k0 + 32, cur ^ 1);

    bf16x8 af[4], bfr[4];
#pragma unroll
    for (int m = 0; m < 4; ++m)
      af[m] = *reinterpret_cast<const bf16x8*>(&As[cur][(wm * 64 + m * 16 + lrow) * 32 + lkb]);
#pragma unroll
    for (int n = 0; n < 4; ++n)
      bfr[n] = *reinterpret_cast<const bf16x8*>(&Bs[cur][(wn * 64 + n * 16 + lrow) * 32 + lkb]);
#pragma unroll
    for (int m = 0; m < 4; ++m)
#pragma unroll
      for (int n = 0; n < 4; ++n)
        acc[m][n] = __builtin_amdgcn_mfma_f32_16x16x32_bf16(af[m], bfr[n], acc[m][n], 0, 0, 0);

    __syncthreads();
    cur ^= 1;
  }

  const int crow = (lane >> 4) * 4;
  const int ccol = lane & 15;
#pragma unroll
  for (int m = 0; m < 4; ++m) {
#pragma unroll
    for (int n = 0; n < 4; ++n) {
      const int gc = n0 + wn * 64 + n * 16 + ccol;
      if (CLAMP_N && gc >= N) continue;
      float bv = HAS_BIAS ? biasb[gc] : 0.f;
#pragma unroll
      for (int r = 0; r < 4; ++r) {
        const int gr = m0 + wm * 64 + m * 16 + crow + r;
        float v = (acc[m][n][r] + bv) * scale;
        long off = (long)b * sC + (long)gr * N + gc;
        if (OUT_BF16)
          ((unsigned short*)Cv)[off] = f2b(v);
        else
          ((float*)Cv)[off] = v;
      }
    }
  }
}

// ---------------- row softmax over P=576, fp32 in -> bf16 out ----------------
__global__ void softmax_kernel(const float* __restrict__ s,
                               unsigned short* __restrict__ attn) {
  const int P = 576;
  long row = (long)blockIdx.x * 4 + (threadIdx.x >> 6);
  int lane = threadIdx.x & 63;
  const float* sr = s + row * P;
  unsigned short* ar = attn + row * P;
  float v[9];
  float mx = -3.0e38f;
#pragma unroll
  for (int j = 0; j < 9; ++j) {
    v[j] = sr[j * 64 + lane];
    mx = fmaxf(mx, v[j]);
  }
#pragma unroll
  for (int o = 32; o > 0; o >>= 1) mx = fmaxf(mx, __shfl_xor(mx, o, 64));
  float sum = 0.f;
#pragma unroll
  for (int j = 0; j < 9; ++j) {
    v[j] = __expf(v[j] - mx);
    sum += v[j];
  }
#pragma unroll
  for (int o = 32; o > 0; o >>= 1) sum += __shfl_xor(sum, o, 64);
  float inv = 1.0f / sum;
#pragma unroll
  for (int j = 0; j < 9; ++j) ar[j * 64 + lane] = f2b(v[j] * inv);
}

extern "C" void kernel_launch(void* const* d_in, const int* in_sizes, int n_in,
                              void* d_out, int out_size, void* d_ws, size_t ws_size,
                              hipStream_t stream) {
  const float* text = (const float*)d_in[0];
  const float* feat = (const float*)d_in[1];
  const float* Wq = (const float*)d_in[2];
  const float* bq = (const float*)d_in[3];
  const float* Wk = (const float*)d_in[4];
  const float* bk = (const float*)d_in[5];
  (void)bk;  // bk's contribution to scores is constant over p -> softmax-invariant

  const int B = 8, T = 2048, P = 576, D = 4096;
  const long nText = (long)B * T * D;  // 67,108,864
  const long nFeat = (long)B * P * D;  // 18,874,368

  char* ws = (char*)d_ws;
  unsigned short* text_b = (unsigned short*)(ws);              // 134,217,728
  unsigned short* feat_b = (unsigned short*)(ws + 134217728);  //  37,748,736
  unsigned short* fT_b   = (unsigned short*)(ws + 171966464);  //  37,748,736
  unsigned short* WqT_b  = (unsigned short*)(ws + 209715200);  //  33,554,432
  unsigned short* WkT_b  = (unsigned short*)(ws + 243269632);  //  33,554,432
  unsigned short* attn_b = (unsigned short*)(ws + 276824064);  //  18,874,368
  float* u               = (float*)(ws + 295698432);           //      16,384
  float* c               = (float*)(ws + 295714816);           //      18,432
  float* scores          = (float*)(ws + 209715200);           // alias over WqT/WkT (dead after W2T)
  unsigned short* W2T_b  = (unsigned short*)d_out;                     // head of d_out
  unsigned short* KW_b   = (unsigned short*)((char*)d_out + 67108864); // +64 MB

  dim3 blk(256);
  cvt_kernel<<<4096, blk, 0, stream>>>(text, text_b, nText / 4);
  cvt_kernel<<<2048, blk, 0, stream>>>(feat, feat_b, nFeat / 4);
  transpose_cvt_kernel<<<dim3(D / 32, P / 32, B), blk, 0, stream>>>(feat, fT_b, P, D);
  transpose_cvt_kernel<<<dim3(D / 32, D / 32, 1), blk, 0, stream>>>(Wq, WqT_b, D, D);
  transpose_cvt_kernel<<<dim3(D / 32, D / 32, 1), blk, 0, stream>>>(Wk, WkT_b, D, D);
  hipMemsetAsync(u, 0, D * sizeof(float), stream);
  gemv_col_kernel<<<dim3(D / 256, 32), blk, 0, stream>>>(Wk, bq, u, D);
  rowdot_kernel<<<(B * P) / 4, blk, 0, stream>>>(feat, u, c, D);

  // W2T[x][y] = sum_d Wq[d,x] Wk[d,y] : 8-phase 256^2 (256 blocks, 1/CU)
  gemm8_nt_kernel<<<dim3(16, 16), dim3(512), 0, stream>>>(
      WqT_b, WkT_b, W2T_b, D, D, D);
  // KW[bp][x] = sum_y feat[bp,y] W2T[x,y] : 8-phase 256^2 (288 blocks)
  gemm8_nt_kernel<<<dim3(16, 18), dim3(512), 0, stream>>>(
      feat_b, W2T_b, KW_b, B * P, D, D);
  // scores[b][t][p] = (text[t,:].KW[b,p,:] + c[b,p]) / 64 : fp32, batch->XCD
  gemm_nt_kernel<0, 1, 1, 1><<<dim3(40, 16, 1), blk, 0, stream>>>(
      text_b, KW_b, scores, c, 1.0f / 64.0f, T, P, D,
      (long)T * D, (long)P * D, (long)T * P, P);
  softmax_kernel<<<(B * T) / 4, blk, 0, stream>>>(scores, attn_b);
  // attended = attn * featT^T : batch->XCD
  gemm_nt_kernel<0, 0, 0, 1><<<dim3(256, 16, 1), blk, 0, stream>>>(
      attn_b, fT_b, (float*)d_out, nullptr, 1.0f, T, D, P,
      (long)T * P, (long)D * P, (long)T * D, 0);
}